// Round 1
// 1895.866 us; speedup vs baseline: 1.0333x; 1.0333x over previous
//
#include <hip/hip_runtime.h>
#include <stdint.h>
#include <stddef.h>

#define M_DIM 8192
#define N_DIM 16384
#define K_DIM 4096
#define NT    64        // K tiles of BK=64

typedef unsigned short u16;
typedef __attribute__((ext_vector_type(8))) short short8;
typedef __attribute__((ext_vector_type(4))) float f32x4;

// fp32 -> bf16, round-to-nearest-even (branchless; inputs are finite normals)
__device__ __forceinline__ u16 f2bf(float f) {
    unsigned int u = __builtin_bit_cast(unsigned int, f);
    return (u16)((u + 0x7FFFu + ((u >> 16) & 1u)) >> 16);
}

// async global->LDS DMA, 16B per lane. LDS dest = wave-uniform base + lane*16.
__device__ __forceinline__ void gl2lds16(const void* g, void* l) {
    __builtin_amdgcn_global_load_lds(
        (const __attribute__((address_space(1))) unsigned int*)g,
        (__attribute__((address_space(3))) unsigned int*)l,
        16, 0, 0);
}

// ---------------- pass 1a: x fp32 -> bf16 ----------------
__global__ __launch_bounds__(256) void convert_x_kernel(
    const float* __restrict__ x, u16* __restrict__ xb) {
    int i = blockIdx.x * 256 + threadIdx.x;   // 8 elements per thread
    const float4* p = (const float4*)x + (size_t)i * 2;
    float4 a = p[0], b = p[1];
    union { u16 u[8]; short8 v; } o;
    o.u[0] = f2bf(a.x); o.u[1] = f2bf(a.y); o.u[2] = f2bf(a.z); o.u[3] = f2bf(a.w);
    o.u[4] = f2bf(b.x); o.u[5] = f2bf(b.y); o.u[6] = f2bf(b.z); o.u[7] = f2bf(b.w);
    *((short8*)xb + i) = o.v;
}

// ---------------- pass 1b: w_bf16 = bf16(qw * group_scale) ----------------
__global__ __launch_bounds__(256) void dequant_w_kernel(
    const float* __restrict__ qw, const float* __restrict__ sc, u16* __restrict__ wb) {
    int i = blockIdx.x * 256 + threadIdx.x;   // 8 k-contiguous elements per thread
    int row = i >> 9;                          // 4096/8 = 512 chunks per row
    int kc = i & 511;                          // chunk index; k = kc*8
    float s = sc[row * 32 + (kc >> 4)];        // group = (kc*8)>>7 = kc>>4
    const float4* p = (const float4*)qw + (size_t)i * 2;
    float4 a = p[0], b = p[1];
    union { u16 u[8]; short8 v; } o;
    o.u[0] = f2bf(a.x * s); o.u[1] = f2bf(a.y * s); o.u[2] = f2bf(a.z * s); o.u[3] = f2bf(a.w * s);
    o.u[4] = f2bf(b.x * s); o.u[5] = f2bf(b.y * s); o.u[6] = f2bf(b.z * s); o.u[7] = f2bf(b.w * s);
    *((short8*)wb + i) = o.v;
}

// ---------------- pass 2: 256x256 8-phase pipelined GEMM (m201 template) ---
// A: [M][K] bf16, B: [N][K] bf16, C: [M][N] fp32.
// 256x256 tile, BK=64; 8 waves (2Mx4N), each wave 128x64 via 8x4 MFMA 16x16x32.
// LDS per matrix per dbuf: [ks(2)][g(2)][128 rows][32 k] u16, 8KiB staging units.
//   g=0 holds tile rows {0-63,128-191}, g=1 holds {64-127,192-255}.
// Slot swizzle: 16B slot s within a 64B row holds logical slot s ^ ((r>>1)&3)
//   (pre-swizzled on the GLOBAL source; LDS dest linear; ds_read applies XOR).
//   -> each consecutive 8-lane group of a ds_read_b128 hits 8 distinct slots.
// Pipeline: unit staged 4-6 phases before first read, >=1 barrier-enforced
//   phase after region's last read. Uniform s_waitcnt vmcnt(9) per phase top.
__global__ __launch_bounds__(512, 2) void gemm_8ph_kernel(
    const u16* __restrict__ A, const u16* __restrict__ B,
    const float* __restrict__ bias, float* __restrict__ C) {
    __shared__ u16 sA[2][16384];   // 64 KB
    __shared__ u16 sB[2][16384];   // 64 KB

    const int tid   = threadIdx.x;
    const int lane  = tid & 63;
    const int wave  = tid >> 6;
    const int wm    = wave >> 2;     // 2 M-waves
    const int wn    = wave & 3;      // 4 N-waves
    const int row16 = lane & 15;
    const int quad  = lane >> 4;

    // bijective XCD swizzle (2048 % 8 == 0)
    const int bid = blockIdx.x;
    const int swz = (bid & 7) * 256 + (bid >> 3);
    const int bx = swz & 63;         // N tile
    const int by = swz >> 6;         // M tile

    // staging source (per-thread constants): thread stages 16B of unit (g,ks)
    //   phys LDS off = tid*16 within unit -> LDS row r = tid>>2, slot = tid&3
    //   logical k-slot = (tid&3) ^ ((tid>>3)&3)  (inverse pre-swizzle)
    const int rlo = (tid >> 2) & 63;
    const int rhi = (tid >> 8) & 1;              // rows 64-127 of unit -> +128
    const int kx  = 8 * ((tid & 3) ^ ((tid >> 3) & 3));
    const u16* Asrc = A + (size_t)(by * 256 + rlo + rhi * 128) * K_DIM + kx;
    const u16* Bsrc = B + (size_t)(bx * 256 + rlo + rhi * 128) * K_DIM + kx;

    // fragment LDS offsets (elements); read applies the same slot XOR
    const int koff = 8 * (quad ^ ((row16 >> 1) & 3));
    const int aoff = (wm * 64 + row16) * 32 + koff;
    const int boff = (wn & 1) * 4096 + ((wn >> 1) * 64 + row16) * 32 + koff;

    f32x4 acc[8][4];
#pragma unroll
    for (int i = 0; i < 8; ++i)
#pragma unroll
        for (int j = 0; j < 4; ++j) acc[i][j] = (f32x4){0.f, 0.f, 0.f, 0.f};
    short8 aF[4], bF[4];

#define STAGE_A(G, KS, T) gl2lds16(Asrc + ((G)*262144 + (size_t)(T)*64 + (KS)*32), \
                                   &sA[(T)&1][(KS)*8192 + (G)*4096 + tid*8]);
#define STAGE_B(G, KS, T) gl2lds16(Bsrc + ((G)*262144 + (size_t)(T)*64 + (KS)*32), \
                                   &sB[(T)&1][(KS)*8192 + (G)*4096 + tid*8]);
#define LDA4(KS, OH) \
    aF[0] = *(const short8*)&sA[cur][(KS)*8192 + (OH)*4096 + aoff +    0]; \
    aF[1] = *(const short8*)&sA[cur][(KS)*8192 + (OH)*4096 + aoff +  512]; \
    aF[2] = *(const short8*)&sA[cur][(KS)*8192 + (OH)*4096 + aoff + 1024]; \
    aF[3] = *(const short8*)&sA[cur][(KS)*8192 + (OH)*4096 + aoff + 1536];
#define LDB4(KS) \
    bF[0] = *(const short8*)&sB[cur][(KS)*8192 + boff +    0]; \
    bF[1] = *(const short8*)&sB[cur][(KS)*8192 + boff +  512]; \
    bF[2] = *(const short8*)&sB[cur][(KS)*8192 + boff + 1024]; \
    bF[3] = *(const short8*)&sB[cur][(KS)*8192 + boff + 1536];
#define MFMA16(OH) \
    acc[(OH)*4+0][0] = __builtin_amdgcn_mfma_f32_16x16x32_bf16(aF[0], bF[0], acc[(OH)*4+0][0],0,0,0); \
    acc[(OH)*4+0][1] = __builtin_amdgcn_mfma_f32_16x16x32_bf16(aF[0], bF[1], acc[(OH)*4+0][1],0,0,0); \
    acc[(OH)*4+0][2] = __builtin_amdgcn_mfma_f32_16x16x32_bf16(aF[0], bF[2], acc[(OH)*4+0][2],0,0,0); \
    acc[(OH)*4+0][3] = __builtin_amdgcn_mfma_f32_16x16x32_bf16(aF[0], bF[3], acc[(OH)*4+0][3],0,0,0); \
    acc[(OH)*4+1][0] = __builtin_amdgcn_mfma_f32_16x16x32_bf16(aF[1], bF[0], acc[(OH)*4+1][0],0,0,0); \
    acc[(OH)*4+1][1] = __builtin_amdgcn_mfma_f32_16x16x32_bf16(aF[1], bF[1], acc[(OH)*4+1][1],0,0,0); \
    acc[(OH)*4+1][2] = __builtin_amdgcn_mfma_f32_16x16x32_bf16(aF[1], bF[2], acc[(OH)*4+1][2],0,0,0); \
    acc[(OH)*4+1][3] = __builtin_amdgcn_mfma_f32_16x16x32_bf16(aF[1], bF[3], acc[(OH)*4+1][3],0,0,0); \
    acc[(OH)*4+2][0] = __builtin_amdgcn_mfma_f32_16x16x32_bf16(aF[2], bF[0], acc[(OH)*4+2][0],0,0,0); \
    acc[(OH)*4+2][1] = __builtin_amdgcn_mfma_f32_16x16x32_bf16(aF[2], bF[1], acc[(OH)*4+2][1],0,0,0); \
    acc[(OH)*4+2][2] = __builtin_amdgcn_mfma_f32_16x16x32_bf16(aF[2], bF[2], acc[(OH)*4+2][2],0,0,0); \
    acc[(OH)*4+2][3] = __builtin_amdgcn_mfma_f32_16x16x32_bf16(aF[2], bF[3], acc[(OH)*4+2][3],0,0,0); \
    acc[(OH)*4+3][0] = __builtin_amdgcn_mfma_f32_16x16x32_bf16(aF[3], bF[0], acc[(OH)*4+3][0],0,0,0); \
    acc[(OH)*4+3][1] = __builtin_amdgcn_mfma_f32_16x16x32_bf16(aF[3], bF[1], acc[(OH)*4+3][1],0,0,0); \
    acc[(OH)*4+3][2] = __builtin_amdgcn_mfma_f32_16x16x32_bf16(aF[3], bF[2], acc[(OH)*4+3][2],0,0,0); \
    acc[(OH)*4+3][3] = __builtin_amdgcn_mfma_f32_16x16x32_bf16(aF[3], bF[3], acc[(OH)*4+3][3],0,0,0);
#define PHASE(VMS, DSL, STG, OH) \
    asm volatile("s_waitcnt vmcnt(" VMS ")" ::: "memory"); \
    DSL \
    STG \
    __builtin_amdgcn_s_barrier(); \
    asm volatile("s_waitcnt lgkmcnt(0)" ::: "memory"); \
    __builtin_amdgcn_sched_barrier(0); \
    __builtin_amdgcn_s_setprio(1); \
    MFMA16(OH) \
    __builtin_amdgcn_s_setprio(0); \
    __builtin_amdgcn_s_barrier();

    // prologue: tile0 fully (8 units) + tile1 first 6 units, steady-state order
    STAGE_B(0,0,0) STAGE_B(1,0,0) STAGE_A(0,0,0) STAGE_A(1,0,0)
    STAGE_A(0,1,0) STAGE_B(0,1,0) STAGE_B(1,1,0) STAGE_A(1,1,0)
    STAGE_B(0,0,1) STAGE_B(1,0,1) STAGE_A(0,0,1) STAGE_A(1,0,1)
    STAGE_A(0,1,1) STAGE_B(0,1,1)
    asm volatile("s_waitcnt vmcnt(9)" ::: "memory");
    __builtin_amdgcn_s_barrier();

    // main loop; per tile v: ph1 stages (ks1,g1) of v+1, ph2 B(ks0) of v+2,
    // ph3 A(ks0) of v+2, ph4 A(ks1,g0)+B(ks1,g0) of v+2. Each staged region's
    // last read was >=1 lgkmcnt-enforced phase earlier.
    for (int v = 0; v < NT - 2; ++v) {
        const int cur = v & 1;
        PHASE("9", LDB4(0) LDA4(0,0), STAGE_B(1,1,v+1) STAGE_A(1,1,v+1), 0)
        PHASE("9", LDA4(0,1),         STAGE_B(0,0,v+2) STAGE_B(1,0,v+2), 1)
        PHASE("9", LDB4(1) LDA4(1,0), STAGE_A(0,0,v+2) STAGE_A(1,0,v+2), 0)
        PHASE("9", LDA4(1,1),         STAGE_A(0,1,v+2) STAGE_B(0,1,v+2), 1)
    }
    { // tile NT-2: only v+1 staging remains; conservative drain waits (tail)
        const int v = NT - 2; const int cur = v & 1;
        PHASE("0", LDB4(0) LDA4(0,0), STAGE_B(1,1,v+1) STAGE_A(1,1,v+1), 0)
        PHASE("0", LDA4(0,1), , 1)
        PHASE("0", LDB4(1) LDA4(1,0), , 0)
        PHASE("0", LDA4(1,1), , 1)
    }
    { // tile NT-1: no staging
        const int cur = (NT - 1) & 1;
        PHASE("0", LDB4(0) LDA4(0,0), , 0)
        PHASE("0", LDA4(0,1), , 1)
        PHASE("0", LDB4(1) LDA4(1,0), , 0)
        PHASE("0", LDA4(1,1), , 1)
    }

    // epilogue: C/D layout col=lane&15, row=quad*4+reg (m89/m91 verified)
    const int rb = by * 256 + wm * 128 + quad * 4;
    const int cb = bx * 256 + wn * 64 + row16;
#pragma unroll
    for (int n = 0; n < 4; ++n) {
        const int col = cb + n * 16;
        const float bv = bias[col];
#pragma unroll
        for (int m = 0; m < 8; ++m) {
            float* cp = C + (size_t)(rb + m * 16) * N_DIM + col;
#pragma unroll
            for (int r = 0; r < 4; ++r) cp[(size_t)r * N_DIM] = acc[m][n][r] + bv;
        }
    }
}

// ---------------- fallback: fused dequant GEMM, fp32 staging (no workspace) ----------------
__global__ __launch_bounds__(256) void gemm_fused_kernel(
    const float* __restrict__ X, const float* __restrict__ QW,
    const float* __restrict__ S, const float* __restrict__ bias,
    float* __restrict__ C) {
    __shared__ u16 fsA[128 * 32];
    __shared__ u16 fsB[128 * 32];

    const int tid   = threadIdx.x;
    const int lane  = tid & 63;
    const int wave  = tid >> 6;
    const int wm    = wave >> 1;
    const int wn    = wave & 1;
    const int row16 = lane & 15;
    const int quad  = lane >> 4;
    const int bx = blockIdx.x;
    const int by = blockIdx.y;

    const int arow  = tid >> 1;
    const int ahalf = (tid & 1) * 16;
    const float* gA = X  + (size_t)(by * 128 + arow) * K_DIM + ahalf;
    const float* gB = QW + (size_t)(bx * 128 + arow) * K_DIM + ahalf;
    const float* gS = S  + (size_t)(bx * 128 + arow) * 32;

    f32x4 zero = {0.f, 0.f, 0.f, 0.f};
    f32x4 acc[4][4];
#pragma unroll
    for (int i = 0; i < 4; ++i)
#pragma unroll
        for (int j = 0; j < 4; ++j) acc[i][j] = zero;

    const int aoff = (wm * 64 + row16) * 32 + quad * 8;
    const int boff = (wn * 64 + row16) * 32 + quad * 8;

    for (int k0 = 0; k0 < K_DIM; k0 += 32) {
        float4 va[4], vb[4];
#pragma unroll
        for (int j = 0; j < 4; ++j) {
            va[j] = *(const float4*)(gA + k0 + j * 4);
            vb[j] = *(const float4*)(gB + k0 + j * 4);
        }
        const float s = gS[k0 >> 7];
        __syncthreads();
        union { u16 u[16]; short8 v[2]; } ua, ub;
#pragma unroll
        for (int j = 0; j < 4; ++j) {
            ua.u[j*4+0] = f2bf(va[j].x);     ua.u[j*4+1] = f2bf(va[j].y);
            ua.u[j*4+2] = f2bf(va[j].z);     ua.u[j*4+3] = f2bf(va[j].w);
            ub.u[j*4+0] = f2bf(vb[j].x * s); ub.u[j*4+1] = f2bf(vb[j].y * s);
            ub.u[j*4+2] = f2bf(vb[j].z * s); ub.u[j*4+3] = f2bf(vb[j].w * s);
        }
        *(short8*)&fsA[arow * 32 + ahalf]     = ua.v[0];
        *(short8*)&fsA[arow * 32 + ahalf + 8] = ua.v[1];
        *(short8*)&fsB[arow * 32 + ahalf]     = ub.v[0];
        *(short8*)&fsB[arow * 32 + ahalf + 8] = ub.v[1];
        __syncthreads();

        short8 aF[4], bF[4];
#pragma unroll
        for (int mi = 0; mi < 4; ++mi) aF[mi] = *(const short8*)&fsA[aoff + mi * 16 * 32];
#pragma unroll
        for (int ni = 0; ni < 4; ++ni) bF[ni] = *(const short8*)&fsB[boff + ni * 16 * 32];
#pragma unroll
        for (int mi = 0; mi < 4; ++mi)
#pragma unroll
            for (int ni = 0; ni < 4; ++ni)
                acc[mi][ni] = __builtin_amdgcn_mfma_f32_16x16x32_bf16(
                    aF[mi], bF[ni], acc[mi][ni], 0, 0, 0);
    }

    const int rb = by * 128 + wm * 64 + quad * 4;
    const int cb = bx * 128 + wn * 64 + row16;
#pragma unroll
    for (int ni = 0; ni < 4; ++ni) {
        const int col = cb + ni * 16;
        const float bv = bias[col];
#pragma unroll
        for (int mi = 0; mi < 4; ++mi) {
            float* cp = C + (size_t)(rb + mi * 16) * N_DIM + col;
#pragma unroll
            for (int r = 0; r < 4; ++r) cp[(size_t)r * N_DIM] = acc[mi][ni][r] + bv;
        }
    }
}

extern "C" void kernel_launch(void* const* d_in, const int* in_sizes, int n_in,
                              void* d_out, int out_size, void* d_ws, size_t ws_size,
                              hipStream_t stream) {
    const float* x    = (const float*)d_in[0];  // [4,2048,4096]
    const float* qw   = (const float*)d_in[1];  // [16384,4096]
    const float* sc   = (const float*)d_in[2];  // [16384,32]
    const float* bias = (const float*)d_in[3];  // [16384]
    float* out = (float*)d_out;                 // [8192,16384]

    const size_t needA = (size_t)M_DIM * K_DIM * sizeof(u16);  // 64 MB
    const size_t needB = (size_t)N_DIM * K_DIM * sizeof(u16);  // 128 MB

    if (ws_size >= needA + needB) {
        u16* xb = (u16*)d_ws;
        u16* wb = xb + (size_t)M_DIM * K_DIM;
        convert_x_kernel<<<(M_DIM * (size_t)K_DIM) / (8 * 256), 256, 0, stream>>>(x, xb);
        dequant_w_kernel<<<(N_DIM * (size_t)K_DIM) / (8 * 256), 256, 0, stream>>>(qw, sc, wb);
        gemm_8ph_kernel<<<dim3((N_DIM / 256) * (M_DIM / 256)), dim3(512), 0, stream>>>(
            xb, wb, bias, out);
    } else {
        dim3 grid(N_DIM / 128, M_DIM / 128);
        gemm_fused_kernel<<<grid, 256, 0, stream>>>(x, qw, sc, bias, out);
    }
}

// Round 2
// 1830.001 us; speedup vs baseline: 1.0705x; 1.0360x over previous
//
#include <hip/hip_runtime.h>
#include <stdint.h>
#include <stddef.h>

#define M_DIM 8192
#define N_DIM 16384
#define K_DIM 4096
#define NT    64        // K tiles of BK=64

typedef unsigned short u16;
typedef __attribute__((ext_vector_type(8))) short short8;
typedef __attribute__((ext_vector_type(4))) float f32x4;

// fp32 -> bf16, round-to-nearest-even (branchless; inputs are finite normals)
__device__ __forceinline__ u16 f2bf(float f) {
    unsigned int u = __builtin_bit_cast(unsigned int, f);
    return (u16)((u + 0x7FFFu + ((u >> 16) & 1u)) >> 16);
}

// async global->LDS DMA, 16B per lane. LDS dest = wave-uniform base + lane*16.
__device__ __forceinline__ void gl2lds16(const void* g, void* l) {
    __builtin_amdgcn_global_load_lds(
        (const __attribute__((address_space(1))) unsigned int*)g,
        (__attribute__((address_space(3))) unsigned int*)l,
        16, 0, 0);
}

// ---------------- pass 1a: x fp32 -> bf16 ----------------
__global__ __launch_bounds__(256) void convert_x_kernel(
    const float* __restrict__ x, u16* __restrict__ xb) {
    int i = blockIdx.x * 256 + threadIdx.x;   // 8 elements per thread
    const float4* p = (const float4*)x + (size_t)i * 2;
    float4 a = p[0], b = p[1];
    union { u16 u[8]; short8 v; } o;
    o.u[0] = f2bf(a.x); o.u[1] = f2bf(a.y); o.u[2] = f2bf(a.z); o.u[3] = f2bf(a.w);
    o.u[4] = f2bf(b.x); o.u[5] = f2bf(b.y); o.u[6] = f2bf(b.z); o.u[7] = f2bf(b.w);
    *((short8*)xb + i) = o.v;
}

// ---------------- pass 1b: w_bf16 = bf16(qw * group_scale) ----------------
__global__ __launch_bounds__(256) void dequant_w_kernel(
    const float* __restrict__ qw, const float* __restrict__ sc, u16* __restrict__ wb) {
    int i = blockIdx.x * 256 + threadIdx.x;   // 8 k-contiguous elements per thread
    int row = i >> 9;                          // 4096/8 = 512 chunks per row
    int kc = i & 511;                          // chunk index; k = kc*8
    float s = sc[row * 32 + (kc >> 4)];        // group = (kc*8)>>7 = kc>>4
    const float4* p = (const float4*)qw + (size_t)i * 2;
    float4 a = p[0], b = p[1];
    union { u16 u[8]; short8 v; } o;
    o.u[0] = f2bf(a.x * s); o.u[1] = f2bf(a.y * s); o.u[2] = f2bf(a.z * s); o.u[3] = f2bf(a.w * s);
    o.u[4] = f2bf(b.x * s); o.u[5] = f2bf(b.y * s); o.u[6] = f2bf(b.z * s); o.u[7] = f2bf(b.w * s);
    *((short8*)wb + i) = o.v;
}

// ---------------- pass 2: 256x256 8-phase pipelined GEMM (m201 template) ---
// A: [M][K] bf16, B: [N][K] bf16, C: [M][N] fp32.
// 256x256 tile, BK=64; 8 waves (2Mx4N), each wave 128x64 via 8x4 MFMA 16x16x32.
// LDS unit = 8KB = [128 rows][32 k] u16 at [buf][ks*8192 + g*4096];
//   g=0 holds tile rows {0-63,128-191}, g=1 holds {64-127,192-255}.
// Slot swizzle: 16B slot s within a 64B row holds logical slot s ^ ((r>>1)&3)
//   (pre-swizzled GLOBAL source; LDS dest linear; ds_read applies same XOR).
// Template-exact cadence: vmcnt(10) at phases 1 and 3 of each tile ONLY
//   (hazard math: at ph1-top the 10 newest loads are exactly those issued
//   after the ph1+ph2-needed units; at ph3-top likewise for ph3+ph4).
// 2-tile unrolled loop -> all LDS/global offsets are compile-time immediates.
__global__ __launch_bounds__(512, 2) void gemm_8ph_kernel(
    const u16* __restrict__ A, const u16* __restrict__ B,
    const float* __restrict__ bias, float* __restrict__ C) {
    __shared__ u16 sA[2][16384];   // 64 KB
    __shared__ u16 sB[2][16384];   // 64 KB

    const int tid   = threadIdx.x;
    const int lane  = tid & 63;
    const int wave  = tid >> 6;
    const int wm    = wave >> 2;     // 2 M-waves
    const int wn    = wave & 3;      // 4 N-waves
    const int row16 = lane & 15;
    const int quad  = lane >> 4;

    // bijective XCD swizzle (2048 % 8 == 0)
    const int bid = blockIdx.x;
    const int swz = (bid & 7) * 256 + (bid >> 3);
    const int bx = swz & 63;         // N tile
    const int by = swz >> 6;         // M tile

    // staging source: thread stages 16B; LDS row r = tid>>2, phys slot = tid&3,
    // logical k-slot = (tid&3) ^ ((tid>>3)&3)  (inverse pre-swizzle)
    const int rlo = (tid >> 2) & 63;
    const int rhi = (tid >> 8) & 1;              // unit rows 64-127 -> tile +128
    const int kx  = 8 * ((tid & 3) ^ ((tid >> 3) & 3));
    const u16* pA0 = A + (size_t)(by * 256 + rlo + rhi * 128) * K_DIM + kx; // g0
    const u16* pB0 = B + (size_t)(bx * 256 + rlo + rhi * 128) * K_DIM + kx;
    const u16* pA1 = pA0 + 262144;   // g1 = +64 tile rows
    const u16* pB1 = pB0 + 262144;
    u16* const dA0 = &sA[0][tid * 8];  u16* const dA1 = &sA[1][tid * 8];
    u16* const dB0 = &sB[0][tid * 8];  u16* const dB1 = &sB[1][tid * 8];

    // fragment read bases (elements); read applies the same slot XOR
    const int koff = 8 * (quad ^ ((row16 >> 1) & 3));
    const int aoff = (wm * 64 + row16) * 32 + koff;
    const int boff = (wn & 1) * 4096 + ((wn >> 1) * 64 + row16) * 32 + koff;
    const u16* const aR0 = &sA[0][aoff];  const u16* const aR1 = &sA[1][aoff];
    const u16* const bR0 = &sB[0][boff];  const u16* const bR1 = &sB[1][boff];

    f32x4 acc[8][4];
#pragma unroll
    for (int i = 0; i < 8; ++i)
#pragma unroll
        for (int j = 0; j < 4; ++j) acc[i][j] = (f32x4){0.f, 0.f, 0.f, 0.f};
    short8 aF[4], bF[4];

// stage unit (G,KS) of tile (base+TO) from running pointer P into dst buf DSTB
#define ST(P, TO, KS, DSTB, G) \
    gl2lds16((P) + ((TO)*64 + (KS)*32), (DSTB) + ((KS)*8192 + (G)*4096));
#define LDA4_(P, KS, OH) \
    aF[0] = *(const short8*)((P) + (KS)*8192 + (OH)*4096 +    0); \
    aF[1] = *(const short8*)((P) + (KS)*8192 + (OH)*4096 +  512); \
    aF[2] = *(const short8*)((P) + (KS)*8192 + (OH)*4096 + 1024); \
    aF[3] = *(const short8*)((P) + (KS)*8192 + (OH)*4096 + 1536);
#define LDB4_(P, KS) \
    bF[0] = *(const short8*)((P) + (KS)*8192 +    0); \
    bF[1] = *(const short8*)((P) + (KS)*8192 +  512); \
    bF[2] = *(const short8*)((P) + (KS)*8192 + 1024); \
    bF[3] = *(const short8*)((P) + (KS)*8192 + 1536);
#define MFMA16(OH) \
    acc[(OH)*4+0][0] = __builtin_amdgcn_mfma_f32_16x16x32_bf16(aF[0], bF[0], acc[(OH)*4+0][0],0,0,0); \
    acc[(OH)*4+0][1] = __builtin_amdgcn_mfma_f32_16x16x32_bf16(aF[0], bF[1], acc[(OH)*4+0][1],0,0,0); \
    acc[(OH)*4+0][2] = __builtin_amdgcn_mfma_f32_16x16x32_bf16(aF[0], bF[2], acc[(OH)*4+0][2],0,0,0); \
    acc[(OH)*4+0][3] = __builtin_amdgcn_mfma_f32_16x16x32_bf16(aF[0], bF[3], acc[(OH)*4+0][3],0,0,0); \
    acc[(OH)*4+1][0] = __builtin_amdgcn_mfma_f32_16x16x32_bf16(aF[1], bF[0], acc[(OH)*4+1][0],0,0,0); \
    acc[(OH)*4+1][1] = __builtin_amdgcn_mfma_f32_16x16x32_bf16(aF[1], bF[1], acc[(OH)*4+1][1],0,0,0); \
    acc[(OH)*4+1][2] = __builtin_amdgcn_mfma_f32_16x16x32_bf16(aF[1], bF[2], acc[(OH)*4+1][2],0,0,0); \
    acc[(OH)*4+1][3] = __builtin_amdgcn_mfma_f32_16x16x32_bf16(aF[1], bF[3], acc[(OH)*4+1][3],0,0,0); \
    acc[(OH)*4+2][0] = __builtin_amdgcn_mfma_f32_16x16x32_bf16(aF[2], bF[0], acc[(OH)*4+2][0],0,0,0); \
    acc[(OH)*4+2][1] = __builtin_amdgcn_mfma_f32_16x16x32_bf16(aF[2], bF[1], acc[(OH)*4+2][1],0,0,0); \
    acc[(OH)*4+2][2] = __builtin_amdgcn_mfma_f32_16x16x32_bf16(aF[2], bF[2], acc[(OH)*4+2][2],0,0,0); \
    acc[(OH)*4+2][3] = __builtin_amdgcn_mfma_f32_16x16x32_bf16(aF[2], bF[3], acc[(OH)*4+2][3],0,0,0); \
    acc[(OH)*4+3][0] = __builtin_amdgcn_mfma_f32_16x16x32_bf16(aF[3], bF[0], acc[(OH)*4+3][0],0,0,0); \
    acc[(OH)*4+3][1] = __builtin_amdgcn_mfma_f32_16x16x32_bf16(aF[3], bF[1], acc[(OH)*4+3][1],0,0,0); \
    acc[(OH)*4+3][2] = __builtin_amdgcn_mfma_f32_16x16x32_bf16(aF[3], bF[2], acc[(OH)*4+3][2],0,0,0); \
    acc[(OH)*4+3][3] = __builtin_amdgcn_mfma_f32_16x16x32_bf16(aF[3], bF[3], acc[(OH)*4+3][3],0,0,0);
#define CORE(OH) \
    __builtin_amdgcn_s_barrier(); \
    asm volatile("s_waitcnt lgkmcnt(0)" ::: "memory"); \
    __builtin_amdgcn_s_setprio(1); \
    MFMA16(OH) \
    __builtin_amdgcn_s_setprio(0); \
    __builtin_amdgcn_s_barrier();
#define VW10 asm volatile("s_waitcnt vmcnt(10)" ::: "memory");
#define VW0  asm volatile("s_waitcnt vmcnt(0)" ::: "memory");

    // prologue: tile0's 8 units + tile1's first 6, in steady-state unit order
    ST(pB0,0,0,dB0,0) ST(pB1,0,0,dB0,1) ST(pA0,0,0,dA0,0) ST(pA1,0,0,dA0,1)
    ST(pA0,0,1,dA0,0) ST(pB0,0,1,dB0,0) ST(pB1,0,1,dB0,1) ST(pA1,0,1,dA0,1)
    ST(pB0,1,0,dB1,0) ST(pB1,1,0,dB1,1) ST(pA0,1,0,dA1,0) ST(pA1,1,0,dA1,1)
    ST(pA0,1,1,dA1,0) ST(pB0,1,1,dB1,0)
    VW10                              // all waves' tile0 ks0 units complete...
    __builtin_amdgcn_s_barrier();     // ...before anyone reads them

    // main loop: 31 iterations x 2 tiles (tiles 0..61); per tile:
    //   ph1 stages (g1,ks1) of t+1; ph2 B(ks0) of t+2; ph3 A(ks0) of t+2;
    //   ph4 A(g0,ks1)+B(g0,ks1) of t+2. Waits: vmcnt(10) at ph1/ph3 only.
#pragma unroll 1
    for (int it = 0; it < (NT - 2) / 2; ++it) {
        // ---- even tile e (buf 0) ----
        VW10 LDB4_(bR0,0) LDA4_(aR0,0,0) ST(pB1,1,1,dB1,1) ST(pA1,1,1,dA1,1) CORE(0)
        LDA4_(aR0,0,1)                   ST(pB0,2,0,dB0,0) ST(pB1,2,0,dB0,1) CORE(1)
        VW10 LDB4_(bR0,1) LDA4_(aR0,1,0) ST(pA0,2,0,dA0,0) ST(pA1,2,0,dA0,1) CORE(0)
        LDA4_(aR0,1,1)                   ST(pA0,2,1,dA0,0) ST(pB0,2,1,dB0,0) CORE(1)
        // ---- odd tile o = e+1 (buf 1) ----
        VW10 LDB4_(bR1,0) LDA4_(aR1,0,0) ST(pB1,2,1,dB0,1) ST(pA1,2,1,dA0,1) CORE(0)
        LDA4_(aR1,0,1)                   ST(pB0,3,0,dB1,0) ST(pB1,3,0,dB1,1) CORE(1)
        VW10 LDB4_(bR1,1) LDA4_(aR1,1,0) ST(pA0,3,0,dA1,0) ST(pA1,3,0,dA1,1) CORE(0)
        LDA4_(aR1,1,1)                   ST(pA0,3,1,dA1,0) ST(pB0,3,1,dB1,0) CORE(1)
        pA0 += 128; pA1 += 128; pB0 += 128; pB1 += 128;
    }
    { // tile 62 (buf 0): stage tile63's last 2 units; conservative drain waits
        VW0 LDB4_(bR0,0) LDA4_(aR0,0,0) ST(pB1,1,1,dB1,1) ST(pA1,1,1,dA1,1) CORE(0)
        LDA4_(aR0,0,1)                                                      CORE(1)
        VW0 LDB4_(bR0,1) LDA4_(aR0,1,0)                                     CORE(0)
        LDA4_(aR0,1,1)                                                      CORE(1)
    }
    { // tile 63 (buf 1): no staging
        VW0 LDB4_(bR1,0) LDA4_(aR1,0,0)                                     CORE(0)
        LDA4_(aR1,0,1)                                                      CORE(1)
        LDB4_(bR1,1) LDA4_(aR1,1,0)                                         CORE(0)
        LDA4_(aR1,1,1)                                                      CORE(1)
    }

    // epilogue: C/D layout col=lane&15, row=quad*4+reg (m89/m91 verified)
    const int rb = by * 256 + wm * 128 + quad * 4;
    const int cb = bx * 256 + wn * 64 + row16;
#pragma unroll
    for (int n = 0; n < 4; ++n) {
        const int col = cb + n * 16;
        const float bv = bias[col];
#pragma unroll
        for (int m = 0; m < 8; ++m) {
            float* cp = C + (size_t)(rb + m * 16) * N_DIM + col;
#pragma unroll
            for (int r = 0; r < 4; ++r) cp[(size_t)r * N_DIM] = acc[m][n][r] + bv;
        }
    }
}

// ---------------- fallback: fused dequant GEMM, fp32 staging (no workspace) ----------------
__global__ __launch_bounds__(256) void gemm_fused_kernel(
    const float* __restrict__ X, const float* __restrict__ QW,
    const float* __restrict__ S, const float* __restrict__ bias,
    float* __restrict__ C) {
    __shared__ u16 fsA[128 * 32];
    __shared__ u16 fsB[128 * 32];

    const int tid   = threadIdx.x;
    const int lane  = tid & 63;
    const int wave  = tid >> 6;
    const int wm    = wave >> 1;
    const int wn    = wave & 1;
    const int row16 = lane & 15;
    const int quad  = lane >> 4;
    const int bx = blockIdx.x;
    const int by = blockIdx.y;

    const int arow  = tid >> 1;
    const int ahalf = (tid & 1) * 16;
    const float* gA = X  + (size_t)(by * 128 + arow) * K_DIM + ahalf;
    const float* gB = QW + (size_t)(bx * 128 + arow) * K_DIM + ahalf;
    const float* gS = S  + (size_t)(bx * 128 + arow) * 32;

    f32x4 zero = {0.f, 0.f, 0.f, 0.f};
    f32x4 acc[4][4];
#pragma unroll
    for (int i = 0; i < 4; ++i)
#pragma unroll
        for (int j = 0; j < 4; ++j) acc[i][j] = zero;

    const int aoff = (wm * 64 + row16) * 32 + quad * 8;
    const int boff = (wn * 64 + row16) * 32 + quad * 8;

    for (int k0 = 0; k0 < K_DIM; k0 += 32) {
        float4 va[4], vb[4];
#pragma unroll
        for (int j = 0; j < 4; ++j) {
            va[j] = *(const float4*)(gA + k0 + j * 4);
            vb[j] = *(const float4*)(gB + k0 + j * 4);
        }
        const float s = gS[k0 >> 7];
        __syncthreads();
        union { u16 u[16]; short8 v[2]; } ua, ub;
#pragma unroll
        for (int j = 0; j < 4; ++j) {
            ua.u[j*4+0] = f2bf(va[j].x);     ua.u[j*4+1] = f2bf(va[j].y);
            ua.u[j*4+2] = f2bf(va[j].z);     ua.u[j*4+3] = f2bf(va[j].w);
            ub.u[j*4+0] = f2bf(vb[j].x * s); ub.u[j*4+1] = f2bf(vb[j].y * s);
            ub.u[j*4+2] = f2bf(vb[j].z * s); ub.u[j*4+3] = f2bf(vb[j].w * s);
        }
        *(short8*)&fsA[arow * 32 + ahalf]     = ua.v[0];
        *(short8*)&fsA[arow * 32 + ahalf + 8] = ua.v[1];
        *(short8*)&fsB[arow * 32 + ahalf]     = ub.v[0];
        *(short8*)&fsB[arow * 32 + ahalf + 8] = ub.v[1];
        __syncthreads();

        short8 aF[4], bF[4];
#pragma unroll
        for (int mi = 0; mi < 4; ++mi) aF[mi] = *(const short8*)&fsA[aoff + mi * 16 * 32];
#pragma unroll
        for (int ni = 0; ni < 4; ++ni) bF[ni] = *(const short8*)&fsB[boff + ni * 16 * 32];
#pragma unroll
        for (int mi = 0; mi < 4; ++mi)
#pragma unroll
            for (int ni = 0; ni < 4; ++ni)
                acc[mi][ni] = __builtin_amdgcn_mfma_f32_16x16x32_bf16(
                    aF[mi], bF[ni], acc[mi][ni], 0, 0, 0);
    }

    const int rb = by * 128 + wm * 64 + quad * 4;
    const int cb = bx * 128 + wn * 64 + row16;
#pragma unroll
    for (int ni = 0; ni < 4; ++ni) {
        const int col = cb + ni * 16;
        const float bv = bias[col];
#pragma unroll
        for (int mi = 0; mi < 4; ++mi) {
            float* cp = C + (size_t)(rb + mi * 16) * N_DIM + col;
#pragma unroll
            for (int r = 0; r < 4; ++r) cp[(size_t)r * N_DIM] = acc[mi][ni][r] + bv;
        }
    }
}

extern "C" void kernel_launch(void* const* d_in, const int* in_sizes, int n_in,
                              void* d_out, int out_size, void* d_ws, size_t ws_size,
                              hipStream_t stream) {
    const float* x    = (const float*)d_in[0];  // [4,2048,4096]
    const float* qw   = (const float*)d_in[1];  // [16384,4096]
    const float* sc   = (const float*)d_in[2];  // [16384,32]
    const float* bias = (const float*)d_in[3];  // [16384]
    float* out = (float*)d_out;                 // [8192,16384]

    const size_t needA = (size_t)M_DIM * K_DIM * sizeof(u16);  // 64 MB
    const size_t needB = (size_t)N_DIM * K_DIM * sizeof(u16);  // 128 MB

    if (ws_size >= needA + needB) {
        u16* xb = (u16*)d_ws;
        u16* wb = xb + (size_t)M_DIM * K_DIM;
        convert_x_kernel<<<(M_DIM * (size_t)K_DIM) / (8 * 256), 256, 0, stream>>>(x, xb);
        dequant_w_kernel<<<(N_DIM * (size_t)K_DIM) / (8 * 256), 256, 0, stream>>>(qw, sc, wb);
        gemm_8ph_kernel<<<dim3((N_DIM / 256) * (M_DIM / 256)), dim3(512), 0, stream>>>(
            xb, wb, bias, out);
    } else {
        dim3 grid(N_DIM / 128, M_DIM / 128);
        gemm_fused_kernel<<<grid, 256, 0, stream>>>(x, qw, sc, bias, out);
    }
}